// Round 13
// baseline (15.808 us; speedup 1.0000x reference)
//
#include <hip/hip_runtime.h>

// Chamfer distance, B=8, N=M=4096, fp32 in/out — fused MFMA (f16, K=8) path.
//   d^2 = |q~|^2 + (hi+lo) - 2 q~.b~   via  v_mfma_f32_32x32x8_f16
//   A (32x8) = db tile: lanes 0-31 row=lane k=0..3 {x,y,z,hi};
//                       lanes 32-63 row=lane-32 k=4..7 {lo,0,0,0}
//   B (8x32) = queries: lanes 0-31 col=lane k=0..3 {-2x,-2y,-2z,1};
//                       lanes 32-63 col=lane-32 k=4..7 {1,0,0,0}
//   C: col = lane&31 (query); 16 regs x 2 lane-halves cover all 32 db rows.
// K1 cd_mfma: 256 blocks x 512 thr. 32KB LDS: db staged in TWO 2048-pt
//             generations (stage|bar|compute 64 tiles|bar|...) so 4 blocks/CU;
//             2-deep acc + <=64 VGPR (launch_bounds 512,8) -> 8 waves/SIMD.
//             Per wave: v_min3 tree-fold, sqrt+sum, block reduce -> Bsum[256].
// K2 cd_final: 1 block (256 thr) sums Bsum deterministically -> loss.

typedef _Float16 f16x4 __attribute__((ext_vector_type(4)));
typedef _Float16 f16x8 __attribute__((ext_vector_type(8)));
typedef float    f32x16 __attribute__((ext_vector_type(16)));

#define BATCH 8
#define NPTS 4096
#define THREADS 512
#define WAVES 8
#define HALF_PTS 2048                // db points per LDS generation
#define HALF_TILES (HALF_PTS/32)     // 64
#define K1_BLOCKS 256                // 16 dirb x 16 coltile-groups

__device__ __forceinline__ float min3f(float a, float b, float c) {
    return fminf(fminf(a, b), c);    // -> v_min3_f32
}

__global__ __launch_bounds__(THREADS, 8) void cd_mfma(
        const float* __restrict__ pred,
        const float* __restrict__ targ,
        float* __restrict__ Bsum) {
    __shared__ uint4 sdb[HALF_PTS];      // 32 KB packed db (one generation)
    __shared__ float wred[WAVES];
    const int bx   = blockIdx.x;         // 0..255
    const int tid  = threadIdx.x;
    const int dirb = bx >> 4;            // 0..15
    const int ctg  = bx & 15;            // 0..15
    const int wave = tid >> 6;           // 0..7
    const int lane = tid & 63;
    const int dir  = dirb >> 3;
    const int b    = dirb & 7;
    const float* Qraw = (dir ? targ : pred) + (size_t)b * NPTS * 3;
    const float* Draw = (dir ? pred : targ) + (size_t)b * NPTS * 3;

    // query packet (built once, before first barrier)
    const int q = (ctg * WAVES + wave) * 32 + (lane & 31);
    const float* qp = Qraw + (size_t)q * 3;
    _Float16 qhx = (_Float16)qp[0], qhy = (_Float16)qp[1], qhz = (_Float16)qp[2];
    float xr = (float)qhx, yr = (float)qhy, zr = (float)qhz;
    float nq = fmaf(xr, xr, fmaf(yr, yr, zr * zr));
    _Float16 mx = (_Float16)(-2.f * xr), my = (_Float16)(-2.f * yr),
             mz = (_Float16)(-2.f * zr), one = (_Float16)1.f, zz = (_Float16)0.f;
    f16x4 Bf = (lane < 32) ? (f16x4){mx, my, mz, one}
                           : (f16x4){one, zz, zz, zz};

    const f32x16 Z = {};
    const float inf = __uint_as_float(0x7F800000u);
    float m = inf;
    auto fold = [&](const f32x16& a) {
        float s0 = min3f(a[0],  a[1],  a[2]);
        float s1 = min3f(a[3],  a[4],  a[5]);
        float s2 = min3f(a[6],  a[7],  a[8]);
        float s3 = min3f(a[9],  a[10], a[11]);
        float s4 = min3f(a[12], a[13], a[14]);
        float t0 = min3f(s0, s1, s2);
        float t1 = min3f(s3, s4, a[15]);
        m = min3f(m, t0, t1);
    };

    const char* sb = (const char*)sdb;
    const int off0 = (lane & 31) * 16 + ((lane >> 5) << 3);

    #pragma unroll 1
    for (int h = 0; h < 2; ++h) {
        if (h) __syncthreads();          // compute(h-1) done before overwrite

        // stage + f16-pack this half: packet = {x,y,z,hi | lo,0,0,0}
        for (int i = tid; i < HALF_PTS; i += THREADS) {
            const float* p = Draw + (size_t)(h * HALF_PTS + i) * 3;
            _Float16 hx = (_Float16)p[0], hy = (_Float16)p[1], hz = (_Float16)p[2];
            float xf = (float)hx, yf = (float)hy, zf = (float)hz;
            float w  = fmaf(xf, xf, fmaf(yf, yf, zf * zf));
            _Float16 hhi = (_Float16)w;
            _Float16 hlo = (_Float16)(w - (float)hhi);
            f16x8 pkt = {hx, hy, hz, hhi, hlo,
                         (_Float16)0.f, (_Float16)0.f, (_Float16)0.f};
            sdb[i] = __builtin_bit_cast(uint4, pkt);
        }
        __syncthreads();

        // 64 tiles, 2-deep MFMA pipeline
        int off = off0;
        auto rd = [&]() { f16x4 v = *(const f16x4*)(sb + off); off += 512; return v; };
        f32x16 acc0 = __builtin_amdgcn_mfma_f32_32x32x8f16(rd(), Bf, Z, 0, 0, 0);
        f32x16 acc1 = __builtin_amdgcn_mfma_f32_32x32x8f16(rd(), Bf, Z, 0, 0, 0);
        #pragma unroll 4
        for (int j = 2; j < HALF_TILES; j += 2) {
            fold(acc0);
            acc0 = __builtin_amdgcn_mfma_f32_32x32x8f16(rd(), Bf, Z, 0, 0, 0);
            fold(acc1);
            acc1 = __builtin_amdgcn_mfma_f32_32x32x8f16(rd(), Bf, Z, 0, 0, 0);
        }
        fold(acc0);
        fold(acc1);
        __syncthreads();                 // all reads done before next stage
    }

    // epilogue: merge lane-halves, add |q~|^2, sqrt, sum 32 queries
    m = fminf(m, __shfl_xor(m, 32, 64));
    float d = sqrtf(fmaxf(m + nq, 0.f));
    d += __shfl_xor(d, 16, 64);
    d += __shfl_xor(d,  8, 64);
    d += __shfl_xor(d,  4, 64);
    d += __shfl_xor(d,  2, 64);
    d += __shfl_xor(d,  1, 64);
    if (lane == 0) wred[wave] = d;
    __syncthreads();
    if (tid == 0) {
        float s = ((wred[0] + wred[1]) + (wred[2] + wred[3]))
                + ((wred[4] + wred[5]) + (wred[6] + wred[7]));
        Bsum[bx] = s;
    }
}

__global__ __launch_bounds__(256) void cd_final(
        const float* __restrict__ Bsum, float* __restrict__ out) {
    const int tid = threadIdx.x;
    float s = Bsum[tid];             // 256 values, one per thread
    __shared__ float red[256];
    red[tid] = s;
    __syncthreads();
    for (int off = 128; off > 0; off >>= 1) {
        if (tid < off) red[tid] += red[tid + off];
        __syncthreads();
    }
    if (tid == 0) out[0] = red[0] * (1.0f / (float)(BATCH * NPTS));
}

extern "C" void kernel_launch(void* const* d_in, const int* in_sizes, int n_in,
                              void* d_out, int out_size, void* d_ws, size_t ws_size,
                              hipStream_t stream) {
    const float* pred = (const float*)d_in[0];
    const float* targ = (const float*)d_in[1];
    float* Bsum = (float*)d_ws;     // 1 KB
    float* out  = (float*)d_out;

    cd_mfma<<<K1_BLOCKS, THREADS, 0, stream>>>(pred, targ, Bsum);
    cd_final<<<1, 256, 0, stream>>>(Bsum, out);
}